// Round 2
// baseline (1250.547 us; speedup 1.0000x reference)
//
#include <hip/hip_runtime.h>

#define C_N 64
#define I_N 64
#define R_N 36
#define L_N 40
#define D_N 1024
#define S_N 256

#define ATT_LD 40
#define P_LD   72     // GEMM2 A: cols 0..63 used (r padded), rows 48
#define SIM_LD 520    // 512 data + 8 pad; row = 1040 B = 260 dw, %32=4 -> 2-way free on b128

typedef float f4 __attribute__((ext_vector_type(4)));
typedef short s16x8 __attribute__((ext_vector_type(8)));

__device__ __forceinline__ unsigned short f2bs(float f) {
    union { float f; unsigned u; } v; v.f = f;
    unsigned r = v.u + 0x7FFFu + ((v.u >> 16) & 1u);
    return (unsigned short)(r >> 16);
}
__device__ __forceinline__ float bs2f(unsigned short s) {
    union { unsigned u; float f; } v; v.u = ((unsigned)s) << 16;
    return v.f;
}

// ws layout (shorts):
//   img_b  [0،        2359296)   bf16 img  [i][r][d]
//   cap_b  [2359296,  4980736)   bf16 cap  [c][l][d]
//   wt     [4980736,  5242880)   bf16 W^T  [s][d]
//   img_t  [5242880,  8388608)   bf16 img  [i][d][r48]  (rows 36..47 zero)
//   slack  [8388608,  8388672)   zeros (GEMM2 k-spill reads land here)
#define OFF_CAP 2359296
#define OFF_WT  4980736
#define OFF_IMT 5242880
#define OFF_END 8388608

__global__ void k_convert(const float* __restrict__ img, const float* __restrict__ cap,
                          const float* __restrict__ W, unsigned short* __restrict__ ws) {
    int t = blockIdx.x * 256 + threadIdx.x;
    if (t < I_N * R_N * D_N) ws[t] = f2bs(img[t]);                       // img_b
    if (t < C_N * L_N * D_N) ws[OFF_CAP + t] = f2bs(cap[t]);             // cap_b
    if (t < D_N * S_N) {                                                 // wt[s][d]
        int d = t >> 8, s = t & 255;
        ws[OFF_WT + s * D_N + d] = f2bs(W[t]);
    }
    if (t < I_N * R_N * D_N) {                                           // img_t values
        int i = t / (R_N * D_N), r = (t / D_N) % R_N, d = t % D_N;
        ws[OFF_IMT + (i * D_N + d) * 48 + r] = f2bs(img[t]);
    }
    if (t < I_N * D_N * 12) {                                            // img_t zero rows
        int i = t / (D_N * 12), d = (t / 12) % D_N, rr = t % 12;
        ws[OFF_IMT + (i * D_N + d) * 48 + 36 + rr] = 0;
    }
    if (t < 64) ws[OFF_END + t] = 0;                                     // slack
}

__global__ __launch_bounds__(512, 4)
void k_fused(const unsigned short* __restrict__ img_b,
             const unsigned short* __restrict__ cap_b,
             const unsigned short* __restrict__ wt,
             const unsigned short* __restrict__ img_t,
             const int* __restrict__ cap_lens,
             const float* __restrict__ bias,
             float* __restrict__ out) {
    __shared__ __align__(16) float          s_attn[48 * ATT_LD];   // attn^T [l][r]
    __shared__ __align__(16) unsigned short s_p[48 * P_LD];        // probs  [l][r] bf16
    __shared__ __align__(16) unsigned short s_sim[48 * SIM_LD];    // sim half [l][d512]
    __shared__ float s_norm[48];    // 1/||wc_l||
    __shared__ float s_norm2[48];   // epilogue sumsq

    const int i = blockIdx.x, c = blockIdx.y;
    const int tid  = threadIdx.x;
    const int wave = tid >> 6, lane = tid & 63;
    const int q = lane >> 4, ln16 = lane & 15;

    const unsigned short* capc = cap_b + c * (L_N * D_N);
    const unsigned short* imgc = img_b + i * (R_N * D_N);
    const unsigned short* imtc = img_t + (size_t)i * D_N * 48;

    // ---- phase 0: init ----
    for (int k = tid; k < 48 * ATT_LD; k += 512) s_attn[k] = 0.f;
    for (int k = tid; k < 48 * P_LD; k += 512) s_p[k] = 0;
    if (tid < 48) { s_norm[tid] = 0.f; s_norm2[tid] = 0.f; }
    __syncthreads();

    // ---- phase 1: GEMM1  attn^T[l][r] = sum_d cap[l][d]*img[r][d], K split 8 waves ----
    {
        f4 acc[3][3] = {};
        const int kw = wave * 128;
        #pragma unroll
        for (int ks = 0; ks < 4; ++ks) {
            const int kb = kw + ks * 32 + q * 8;
            s16x8 af[3], bfr[3];
            #pragma unroll
            for (int mt = 0; mt < 3; ++mt) {
                int l = mt * 16 + ln16;
                af[mt] = (l < L_N) ? *(const s16x8*)(capc + l * D_N + kb) : (s16x8)0;
            }
            #pragma unroll
            for (int nt = 0; nt < 3; ++nt) {
                int r = nt * 16 + ln16;
                bfr[nt] = (r < R_N) ? *(const s16x8*)(imgc + r * D_N + kb) : (s16x8)0;
            }
            #pragma unroll
            for (int mt = 0; mt < 3; ++mt)
                #pragma unroll
                for (int nt = 0; nt < 3; ++nt)
                    acc[mt][nt] = __builtin_amdgcn_mfma_f32_16x16x32_bf16(af[mt], bfr[nt], acc[mt][nt], 0, 0, 0);
        }
        #pragma unroll
        for (int mt = 0; mt < 3; ++mt)
            #pragma unroll
            for (int nt = 0; nt < 3; ++nt)
                #pragma unroll
                for (int j = 0; j < 4; ++j) {
                    int l = mt * 16 + q * 4 + j;
                    int r = nt * 16 + ln16;
                    if (l < L_N && r < R_N) atomicAdd(&s_attn[l * ATT_LD + r], acc[mt][nt][j]);
                }
    }
    __syncthreads();

    // ---- phase 2a: leaky_relu + l2norm over words (column per region) ----
    if (tid < R_N) {
        float ss = 0.f;
        #pragma unroll
        for (int l = 0; l < L_N; ++l) {
            float v = s_attn[l * ATT_LD + tid];
            v = (v > 0.f) ? v : 0.1f * v;
            s_attn[l * ATT_LD + tid] = v;
            ss += v * v;
        }
        float inv = 1.f / (sqrtf(ss) + 1e-8f);
        #pragma unroll
        for (int l = 0; l < L_N; ++l) s_attn[l * ATT_LD + tid] *= inv;
    }
    __syncthreads();
    // ---- phase 2b: softmax over regions (row per word) -> s_p bf16 ----
    if (tid < L_N) {
        float mx = -1e30f;
        #pragma unroll
        for (int r = 0; r < R_N; ++r) mx = fmaxf(mx, 9.f * s_attn[tid * ATT_LD + r]);
        float sum = 0.f;
        float ex[R_N];
        #pragma unroll
        for (int r = 0; r < R_N; ++r) {
            float e = __expf(9.f * s_attn[tid * ATT_LD + r] - mx);
            ex[r] = e; sum += e;
        }
        float inv = 1.f / sum;
        #pragma unroll
        for (int r = 0; r < R_N; ++r) s_p[tid * P_LD + r] = f2bs(ex[r] * inv);
    }
    __syncthreads();

    // ---- phase 3: norm pass — wc sumsq only (wave owns 128 d-cols, 4 sub-chunks) ----
    {
        float rs[3][4] = {};
        #pragma unroll
        for (int s4 = 0; s4 < 4; ++s4) {
            const int dbase = wave * 128 + s4 * 32;
            f4 a2[3][2] = {};
            #pragma unroll
            for (int ks = 0; ks < 2; ++ks) {
                const int kb = ks * 32 + q * 8;
                s16x8 pf[3];
                #pragma unroll
                for (int mt = 0; mt < 3; ++mt)
                    pf[mt] = *(const s16x8*)(s_p + (mt * 16 + ln16) * P_LD + kb);
                #pragma unroll
                for (int nt = 0; nt < 2; ++nt) {
                    const int dcol = dbase + nt * 16 + ln16;
                    s16x8 bfr = *(const s16x8*)(imtc + dcol * 48 + kb);
                    #pragma unroll
                    for (int mt = 0; mt < 3; ++mt)
                        a2[mt][nt] = __builtin_amdgcn_mfma_f32_16x16x32_bf16(pf[mt], bfr, a2[mt][nt], 0, 0, 0);
                }
            }
            #pragma unroll
            for (int mt = 0; mt < 3; ++mt)
                #pragma unroll
                for (int j = 0; j < 4; ++j)
                    rs[mt][j] += a2[mt][0][j] * a2[mt][0][j] + a2[mt][1][j] * a2[mt][1][j];
        }
        #pragma unroll
        for (int mt = 0; mt < 3; ++mt)
            #pragma unroll
            for (int j = 0; j < 4; ++j) {
                float s = rs[mt][j];
                #pragma unroll
                for (int o = 1; o < 16; o <<= 1) s += __shfl_xor(s, o, 64);
                if (ln16 == 0) atomicAdd(&s_norm[mt * 16 + q * 4 + j], s);
            }
    }
    __syncthreads();
    if (tid < 48) s_norm[tid] = 1.f / (sqrtf(s_norm[tid]) + 1e-8f);
    __syncthreads();

    // ---- phase 4: two halves — recompute wc chunk, sim -> LDS, GEMM3 partial ----
    f4 acc3[3][2] = {};
    #pragma unroll 1
    for (int H = 0; H < 2; ++H) {
        #pragma unroll
        for (int s4 = 0; s4 < 2; ++s4) {
            const int dbase = H * 512 + wave * 64 + s4 * 32;
            f4 a2[3][2] = {};
            #pragma unroll
            for (int ks = 0; ks < 2; ++ks) {
                const int kb = ks * 32 + q * 8;
                s16x8 pf[3];
                #pragma unroll
                for (int mt = 0; mt < 3; ++mt)
                    pf[mt] = *(const s16x8*)(s_p + (mt * 16 + ln16) * P_LD + kb);
                #pragma unroll
                for (int nt = 0; nt < 2; ++nt) {
                    const int dcol = dbase + nt * 16 + ln16;
                    s16x8 bfr = *(const s16x8*)(imtc + dcol * 48 + kb);
                    #pragma unroll
                    for (int mt = 0; mt < 3; ++mt)
                        a2[mt][nt] = __builtin_amdgcn_mfma_f32_16x16x32_bf16(pf[mt], bfr, a2[mt][nt], 0, 0, 0);
                }
            }
            #pragma unroll
            for (int mt = 0; mt < 3; ++mt)
                #pragma unroll
                for (int j = 0; j < 4; ++j) {
                    const int l = mt * 16 + q * 4 + j;
                    const float inv = s_norm[l];
                    #pragma unroll
                    for (int nt = 0; nt < 2; ++nt) {
                        const int dcol = dbase + nt * 16 + ln16;
                        float capv = (l < L_N) ? bs2f(capc[l * D_N + dcol]) : 0.f;
                        float dv = a2[mt][nt][j] * inv - capv;
                        s_sim[l * SIM_LD + (dcol - H * 512)] = f2bs(dv * dv);
                    }
                }
        }
        __syncthreads();
        // GEMM3 partial over this K-half; wave owns s-cols [wave*32, wave*32+32)
        #pragma unroll
        for (int ks = 0; ks < 16; ++ks) {
            const int kb = ks * 32 + q * 8;
            s16x8 af[3], bfr[2];
            #pragma unroll
            for (int mt = 0; mt < 3; ++mt)
                af[mt] = *(const s16x8*)(s_sim + (mt * 16 + ln16) * SIM_LD + kb);
            #pragma unroll
            for (int u = 0; u < 2; ++u) {
                const int srow = wave * 32 + u * 16 + ln16;
                bfr[u] = *(const s16x8*)(wt + srow * D_N + H * 512 + kb);
            }
            #pragma unroll
            for (int mt = 0; mt < 3; ++mt)
                #pragma unroll
                for (int u = 0; u < 2; ++u)
                    acc3[mt][u] = __builtin_amdgcn_mfma_f32_16x16x32_bf16(af[mt], bfr[u], acc3[mt][u], 0, 0, 0);
        }
        __syncthreads();
    }

    // ---- epilogue: +b, relu, l2norm over s, mask, store ----
    const int clen = cap_lens[c];
    float bv[2];
    #pragma unroll
    for (int u = 0; u < 2; ++u) bv[u] = bias[wave * 32 + u * 16 + ln16];
    #pragma unroll
    for (int mt = 0; mt < 3; ++mt)
        #pragma unroll
        for (int j = 0; j < 4; ++j) {
            float s = 0.f;
            #pragma unroll
            for (int u = 0; u < 2; ++u) {
                float v = acc3[mt][u][j] + bv[u];
                v = fmaxf(v, 0.f);
                acc3[mt][u][j] = v;
                s += v * v;
            }
            #pragma unroll
            for (int o = 1; o < 16; o <<= 1) s += __shfl_xor(s, o, 64);
            if (ln16 == 0) atomicAdd(&s_norm2[mt * 16 + q * 4 + j], s);
        }
    __syncthreads();
    if (tid < 48) s_norm2[tid] = 1.f / (sqrtf(s_norm2[tid]) + 1e-8f);
    __syncthreads();
    float* outc = out + (size_t)((c * I_N + i) * L_N) * S_N;
    #pragma unroll
    for (int mt = 0; mt < 3; ++mt)
        #pragma unroll
        for (int j = 0; j < 4; ++j) {
            const int l = mt * 16 + q * 4 + j;
            if (l < L_N) {
                const float sc = (l < clen) ? s_norm2[l] : 0.f;
                #pragma unroll
                for (int u = 0; u < 2; ++u)
                    outc[l * S_N + wave * 32 + u * 16 + ln16] = acc3[mt][u][j] * sc;
            }
        }
}

extern "C" void kernel_launch(void* const* d_in, const int* in_sizes, int n_in,
                              void* d_out, int out_size, void* d_ws, size_t ws_size,
                              hipStream_t stream) {
    const float* img  = (const float*)d_in[0];
    const float* cap  = (const float*)d_in[1];
    const int*   lens = (const int*)d_in[2];
    const float* W    = (const float*)d_in[5];
    const float* bias = (const float*)d_in[6];
    float* out = (float*)d_out;
    unsigned short* ws = (unsigned short*)d_ws;

    k_convert<<<10240, 256, 0, stream>>>(img, cap, W, ws);

    dim3 grid(I_N, C_N);
    k_fused<<<grid, 512, 0, stream>>>(ws, ws + OFF_CAP, ws + OFF_WT, ws + OFF_IMT,
                                      lens, bias, out);
}

// Round 3
// 998.992 us; speedup vs baseline: 1.2518x; 1.2518x over previous
//
#include <hip/hip_runtime.h>

#define C_N 64
#define I_N 64
#define R_N 36
#define L_N 40
#define D_N 1024
#define S_N 256

#define ATT_LD 40
#define P_LD   72
#define SIMQ_LD 280   // 40 rows x 256 data + pad; row=560B (16B-aligned, bank-spread)

// ws layout (shorts):
#define OFF_CAP 2359296
#define OFF_WT  4980736
#define OFF_IMT 5242880
#define OFF_END 8388608   // 64 shorts of zero slack (GEMM2 k-overread lands here)
#define OFF_SIM 8388672   // bf16 sim [ (c*64+i)*40 + l ][ d ]  -> 163840 x 1024
#define M_ALL   (C_N * I_N * L_N)

typedef float f4 __attribute__((ext_vector_type(4)));
typedef short s16x8 __attribute__((ext_vector_type(8)));

__device__ __forceinline__ unsigned short f2bs(float f) {
    union { float f; unsigned u; } v; v.f = f;
    unsigned r = v.u + 0x7FFFu + ((v.u >> 16) & 1u);
    return (unsigned short)(r >> 16);
}
__device__ __forceinline__ float bs2f(unsigned short s) {
    union { unsigned u; float f; } v; v.u = ((unsigned)s) << 16;
    return v.f;
}
__device__ __forceinline__ void async16(const unsigned short* g, unsigned short* l) {
    __builtin_amdgcn_global_load_lds(
        (const __attribute__((address_space(1))) unsigned int*)g,
        (__attribute__((address_space(3))) unsigned int*)l, 16, 0, 0);
}

// ---------------- K0: converts ----------------
__global__ void k_convert(const float* __restrict__ img, const float* __restrict__ cap,
                          const float* __restrict__ W, unsigned short* __restrict__ ws) {
    int t = blockIdx.x * 256 + threadIdx.x;
    if (t < I_N * R_N * D_N) ws[t] = f2bs(img[t]);
    if (t < C_N * L_N * D_N) ws[OFF_CAP + t] = f2bs(cap[t]);
    if (t < D_N * S_N) {                       // W[d][s] -> Wt[s][d]
        int d = t >> 8, s = t & 255;
        ws[OFF_WT + s * D_N + d] = f2bs(W[t]);
    }
    if (t < I_N * R_N * D_N) {                 // img_t [i][d][r48]
        int i = t / (R_N * D_N), r = (t / D_N) % R_N, d = t % D_N;
        ws[OFF_IMT + (i * D_N + d) * 48 + r] = f2bs(img[t]);
    }
    if (t < I_N * D_N * 12) {                  // img_t zero rows 36..47
        int i = t / (D_N * 12), d = (t / 12) % D_N, rr = t % 12;
        ws[OFF_IMT + (i * D_N + d) * 48 + 36 + rr] = 0;
    }
    if (t < 64) ws[OFF_END + t] = 0;
}

// ---------------- A: attention + sim producer, one block per (c,i) ----------------
__global__ __launch_bounds__(512, 8)
void k_attn(const unsigned short* __restrict__ img_b,
            const unsigned short* __restrict__ cap_b,
            const unsigned short* __restrict__ img_t,
            unsigned short* __restrict__ simg) {
    __shared__ __align__(16) float          s_attn[48 * ATT_LD];
    __shared__ __align__(16) unsigned short s_p[48 * P_LD];
    __shared__ __align__(16) unsigned short s_sim[40 * SIMQ_LD];
    __shared__ float s_norm[48];

    const int i = blockIdx.x, c = blockIdx.y;
    const int tid  = threadIdx.x;
    const int wave = tid >> 6, lane = tid & 63;
    const int q = lane >> 4, ln16 = lane & 15;

    const unsigned short* capc = cap_b + c * (L_N * D_N);
    const unsigned short* imgc = img_b + i * (R_N * D_N);
    const unsigned short* imtc = img_t + (size_t)i * D_N * 48;

    for (int k = tid; k < 48 * ATT_LD; k += 512) s_attn[k] = 0.f;
    for (int k = tid; k < 48 * P_LD; k += 512) s_p[k] = 0;
    if (tid < 48) s_norm[tid] = 0.f;
    __syncthreads();

    // phase 1: attn^T[l][r] = cap . img^T, K split over 8 waves
    {
        f4 acc[3][3] = {};
        const int kw = wave * 128;
        #pragma unroll
        for (int ks = 0; ks < 4; ++ks) {
            const int kb = kw + ks * 32 + q * 8;
            s16x8 af[3], bfr[3];
            #pragma unroll
            for (int mt = 0; mt < 3; ++mt) {
                int l = mt * 16 + ln16;
                af[mt] = (l < L_N) ? *(const s16x8*)(capc + l * D_N + kb) : (s16x8)0;
            }
            #pragma unroll
            for (int nt = 0; nt < 3; ++nt) {
                int r = nt * 16 + ln16;
                bfr[nt] = (r < R_N) ? *(const s16x8*)(imgc + r * D_N + kb) : (s16x8)0;
            }
            #pragma unroll
            for (int mt = 0; mt < 3; ++mt)
                #pragma unroll
                for (int nt = 0; nt < 3; ++nt)
                    acc[mt][nt] = __builtin_amdgcn_mfma_f32_16x16x32_bf16(af[mt], bfr[nt], acc[mt][nt], 0, 0, 0);
        }
        #pragma unroll
        for (int mt = 0; mt < 3; ++mt)
            #pragma unroll
            for (int nt = 0; nt < 3; ++nt)
                #pragma unroll
                for (int j = 0; j < 4; ++j) {
                    int l = mt * 16 + q * 4 + j;
                    int r = nt * 16 + ln16;
                    if (l < L_N && r < R_N) atomicAdd(&s_attn[l * ATT_LD + r], acc[mt][nt][j]);
                }
    }
    __syncthreads();

    // phase 2a: leaky_relu + l2norm over words
    if (tid < R_N) {
        float ss = 0.f;
        #pragma unroll
        for (int l = 0; l < L_N; ++l) {
            float v = s_attn[l * ATT_LD + tid];
            v = (v > 0.f) ? v : 0.1f * v;
            s_attn[l * ATT_LD + tid] = v;
            ss += v * v;
        }
        float inv = 1.f / (sqrtf(ss) + 1e-8f);
        #pragma unroll
        for (int l = 0; l < L_N; ++l) s_attn[l * ATT_LD + tid] *= inv;
    }
    __syncthreads();
    // phase 2b: softmax over regions -> s_p bf16
    if (tid < L_N) {
        float mx = -1e30f;
        #pragma unroll
        for (int r = 0; r < R_N; ++r) mx = fmaxf(mx, 9.f * s_attn[tid * ATT_LD + r]);
        float sum = 0.f;
        float ex[R_N];
        #pragma unroll
        for (int r = 0; r < R_N; ++r) {
            float e = __expf(9.f * s_attn[tid * ATT_LD + r] - mx);
            ex[r] = e; sum += e;
        }
        float inv = 1.f / sum;
        #pragma unroll
        for (int r = 0; r < R_N; ++r) s_p[tid * P_LD + r] = f2bs(ex[r] * inv);
    }
    __syncthreads();

    // phase 3: wc sumsq (wave owns 128 d-cols)
    {
        float rs[3][4] = {};
        #pragma unroll
        for (int s4 = 0; s4 < 4; ++s4) {
            const int dbase = wave * 128 + s4 * 32;
            f4 a2[3][2] = {};
            #pragma unroll
            for (int ks = 0; ks < 2; ++ks) {
                const int kb = ks * 32 + q * 8;
                s16x8 pf[3];
                #pragma unroll
                for (int mt = 0; mt < 3; ++mt)
                    pf[mt] = *(const s16x8*)(s_p + (mt * 16 + ln16) * P_LD + kb);
                #pragma unroll
                for (int nt = 0; nt < 2; ++nt) {
                    const int dcol = dbase + nt * 16 + ln16;
                    s16x8 bfr = *(const s16x8*)(imtc + dcol * 48 + kb);
                    #pragma unroll
                    for (int mt = 0; mt < 3; ++mt)
                        a2[mt][nt] = __builtin_amdgcn_mfma_f32_16x16x32_bf16(pf[mt], bfr, a2[mt][nt], 0, 0, 0);
                }
            }
            #pragma unroll
            for (int mt = 0; mt < 3; ++mt)
                #pragma unroll
                for (int j = 0; j < 4; ++j)
                    rs[mt][j] += a2[mt][0][j] * a2[mt][0][j] + a2[mt][1][j] * a2[mt][1][j];
        }
        #pragma unroll
        for (int mt = 0; mt < 3; ++mt)
            #pragma unroll
            for (int j = 0; j < 4; ++j) {
                float s = rs[mt][j];
                #pragma unroll
                for (int o = 1; o < 16; o <<= 1) s += __shfl_xor(s, o, 64);
                if (ln16 == 0) atomicAdd(&s_norm[mt * 16 + q * 4 + j], s);
            }
    }
    __syncthreads();
    if (tid < 48) s_norm[tid] = 1.f / (sqrtf(s_norm[tid]) + 1e-8f);
    __syncthreads();

    // phase 4: 4 quarters — recompute wc chunk, sim -> LDS, flush coalesced to global
    const int pair = c * I_N + i;
    #pragma unroll 1
    for (int Q = 0; Q < 4; ++Q) {
        const int dbase = Q * 256 + wave * 32;
        f4 a2[3][2] = {};
        #pragma unroll
        for (int ks = 0; ks < 2; ++ks) {
            const int kb = ks * 32 + q * 8;
            s16x8 pf[3];
            #pragma unroll
            for (int mt = 0; mt < 3; ++mt)
                pf[mt] = *(const s16x8*)(s_p + (mt * 16 + ln16) * P_LD + kb);
            #pragma unroll
            for (int nt = 0; nt < 2; ++nt) {
                const int dcol = dbase + nt * 16 + ln16;
                s16x8 bfr = *(const s16x8*)(imtc + dcol * 48 + kb);
                #pragma unroll
                for (int mt = 0; mt < 3; ++mt)
                    a2[mt][nt] = __builtin_amdgcn_mfma_f32_16x16x32_bf16(pf[mt], bfr, a2[mt][nt], 0, 0, 0);
            }
        }
        #pragma unroll
        for (int mt = 0; mt < 3; ++mt)
            #pragma unroll
            for (int j = 0; j < 4; ++j) {
                const int l = mt * 16 + q * 4 + j;
                if (l < L_N) {
                    const float inv = s_norm[l];
                    #pragma unroll
                    for (int nt = 0; nt < 2; ++nt) {
                        const int dcol = dbase + nt * 16 + ln16;
                        float dv = a2[mt][nt][j] * inv - bs2f(capc[l * D_N + dcol]);
                        s_sim[l * SIMQ_LD + (dcol - Q * 256)] = f2bs(dv * dv);
                    }
                }
            }
        __syncthreads();
        for (int u = tid; u < L_N * 32; u += 512) {      // 16B units: 40 rows x 512 B
            int l = u >> 5, cg = u & 31;
            *(s16x8*)(simg + (size_t)(pair * L_N + l) * D_N + Q * 256 + cg * 8) =
                *(const s16x8*)(s_sim + l * SIMQ_LD + cg * 8);
        }
        __syncthreads();
    }
}

// ---------------- B: GEMM3  out = l2norm(relu(sim @ W + b)) * mask ----------------
// M=163840, K=1024, N=256. Tile 128x256, BK=64, 8 waves (2 M-groups x 4 N-groups).
__global__ __launch_bounds__(512, 4)
void k_gemm3(const unsigned short* __restrict__ simg,
             const unsigned short* __restrict__ wt,
             const int* __restrict__ cap_lens,
             const float* __restrict__ bias,
             float* __restrict__ out) {
    __shared__ __align__(16) unsigned short sA[128 * 64];   // 16 KB, XOR-swizzled cols
    __shared__ __align__(16) unsigned short sB[256 * 64];   // 32 KB
    __shared__ float s_sum[128];

    const int tid = threadIdx.x;
    const int w = tid >> 6, lane = tid & 63;
    const int ln16 = lane & 15, q = lane >> 4;
    const int wm = (w >> 2) * 64, wn = (w & 3) * 64;
    const int m0 = blockIdx.x * 128;
    const int cgg = ((lane & 7) ^ (lane >> 3)) << 3;   // swizzled source col (shorts)
    const int lrow8 = lane >> 3;
    const int rx = ln16 & 7;                            // row&7 for fragment reads

    if (tid < 128) s_sum[tid] = 0.f;

    f4 acc[4][4] = {};
    #pragma unroll 1
    for (int kc = 0; kc < 16; ++kc) {
        const int kofs = kc * 64;
        // stage A: 128x64, 2 waves-iterations
        #pragma unroll
        for (int it = 0; it < 2; ++it) {
            int row = it * 64 + w * 8 + lrow8;
            async16(simg + (size_t)(m0 + row) * D_N + kofs + cgg,
                    sA + (it * 512 + w * 64) * 8);
        }
        // stage B: 256x64, 4 iterations
        #pragma unroll
        for (int it = 0; it < 4; ++it) {
            int row = it * 64 + w * 8 + lrow8;
            async16(wt + (size_t)row * D_N + kofs + cgg,
                    sB + (it * 512 + w * 64) * 8);
        }
        __syncthreads();
        #pragma unroll
        for (int ks = 0; ks < 2; ++ks) {
            const int g = ks * 4 + q;
            s16x8 af[4], bf[4];
            #pragma unroll
            for (int mt = 0; mt < 4; ++mt) {
                int row = wm + mt * 16 + ln16;
                af[mt] = *(const s16x8*)(sA + row * 64 + ((g ^ rx) << 3));
            }
            #pragma unroll
            for (int nt = 0; nt < 4; ++nt) {
                int row = wn + nt * 16 + ln16;
                bf[nt] = *(const s16x8*)(sB + row * 64 + ((g ^ rx) << 3));
            }
            #pragma unroll
            for (int mt = 0; mt < 4; ++mt)
                #pragma unroll
                for (int nt = 0; nt < 4; ++nt)
                    acc[mt][nt] = __builtin_amdgcn_mfma_f32_16x16x32_bf16(af[mt], bf[nt], acc[mt][nt], 0, 0, 0);
        }
        __syncthreads();
    }

    // epilogue: +bias, relu, sumsq across s (cross-wave via LDS), l2norm, mask, store
    float bv[4];
    #pragma unroll
    for (int nt = 0; nt < 4; ++nt) bv[nt] = bias[wn + nt * 16 + ln16];
    #pragma unroll
    for (int mt = 0; mt < 4; ++mt)
        #pragma unroll
        for (int j = 0; j < 4; ++j) {
            float s = 0.f;
            #pragma unroll
            for (int nt = 0; nt < 4; ++nt) {
                float v = acc[mt][nt][j] + bv[nt];
                v = fmaxf(v, 0.f);
                acc[mt][nt][j] = v;
                s += v * v;
            }
            #pragma unroll
            for (int o = 1; o < 16; o <<= 1) s += __shfl_xor(s, o, 64);
            if (ln16 == 0) atomicAdd(&s_sum[wm + mt * 16 + q * 4 + j], s);
        }
    __syncthreads();
    if (tid < 128) {
        int grow = m0 + tid;
        int c = grow / (I_N * L_N);
        int l = grow % L_N;
        float inv = 1.f / (sqrtf(s_sum[tid]) + 1e-8f);
        s_sum[tid] = (l < cap_lens[c]) ? inv : 0.f;
    }
    __syncthreads();
    #pragma unroll
    for (int mt = 0; mt < 4; ++mt)
        #pragma unroll
        for (int j = 0; j < 4; ++j) {
            const int rt = wm + mt * 16 + q * 4 + j;
            const float sc = s_sum[rt];
            #pragma unroll
            for (int nt = 0; nt < 4; ++nt)
                out[(size_t)(m0 + rt) * S_N + wn + nt * 16 + ln16] = acc[mt][nt][j] * sc;
        }
}

extern "C" void kernel_launch(void* const* d_in, const int* in_sizes, int n_in,
                              void* d_out, int out_size, void* d_ws, size_t ws_size,
                              hipStream_t stream) {
    const float* img  = (const float*)d_in[0];
    const float* cap  = (const float*)d_in[1];
    const int*   lens = (const int*)d_in[2];
    const float* W    = (const float*)d_in[5];
    const float* bias = (const float*)d_in[6];
    float* out = (float*)d_out;
    unsigned short* ws = (unsigned short*)d_ws;

    k_convert<<<10240, 256, 0, stream>>>(img, cap, W, ws);

    dim3 gridA(I_N, C_N);
    k_attn<<<gridA, 512, 0, stream>>>(ws, ws + OFF_CAP, ws + OFF_IMT, ws + OFF_SIM);

    k_gemm3<<<M_ALL / 128, 512, 0, stream>>>(ws + OFF_SIM, ws + OFF_WT, lens, bias, out);
}